// Round 3
// baseline (311.838 us; speedup 1.0000x reference)
//
#include <hip/hip_runtime.h>
#include <hip/hip_bf16.h>
#include <math.h>
#include <stdint.h>

// ---------- types ----------
typedef __attribute__((ext_vector_type(8))) short short8;     // 8 x bf16 (MFMA A/B frag)
typedef __attribute__((ext_vector_type(4))) float floatx4;    // MFMA C/D frag
typedef __attribute__((ext_vector_type(4))) unsigned short ushort4v;

// ---------- helpers ----------
__device__ __forceinline__ void gload_lds16(const void* g, void* lds) {
    __builtin_amdgcn_global_load_lds(
        (__attribute__((address_space(1))) void*)(g),
        (__attribute__((address_space(3))) void*)(lds), 16, 0, 0);
}
__device__ __forceinline__ float bf16bits_to_f(unsigned short u) {
    union { unsigned int i; float f; } x; x.i = ((unsigned int)u) << 16; return x.f;
}
__device__ __forceinline__ unsigned short f_to_bf16bits(float f) {
    union { float f; unsigned int i; } x; x.f = f;
    unsigned int lsb = (x.i >> 16) & 1u;
    x.i += 0x7fffu + lsb;                      // round-to-nearest-even
    return (unsigned short)(x.i >> 16);
}

// =====================================================================
// fp32 -> bf16: Q,K,V inputs in one dispatch. grid 3*4096, 4 elems/thread.
// =====================================================================
__global__ __launch_bounds__(256) void conv_qkv_kernel(
    const float* __restrict__ Q, const float* __restrict__ K, const float* __restrict__ V,
    unsigned short* __restrict__ out)   // 3 slots, stride 4194304
{
    const int seg = blockIdx.x >> 12;            // /4096
    const int blk = blockIdx.x & 4095;
    const float* src = (seg == 0) ? Q : (seg == 1) ? K : V;
    const int idx = (blk * 256 + threadIdx.x) * 4;
    float4 v = *(const float4*)&src[idx];
    ushort4v o;
    o[0] = f_to_bf16bits(v.x); o[1] = f_to_bf16bits(v.y);
    o[2] = f_to_bf16bits(v.z); o[3] = f_to_bf16bits(v.w);
    *(ushort4v*)&out[(size_t)seg * 4194304 + idx] = o;
}

// W[512x512] x3 and b[512] x3 -> bf16 slots. grid (257, 3).
__global__ __launch_bounds__(256) void conv_wb_kernel(
    const float* __restrict__ Wq, const float* __restrict__ Wk, const float* __restrict__ Wv,
    const float* __restrict__ bq, const float* __restrict__ bk, const float* __restrict__ bv,
    unsigned short* __restrict__ Wo,   // 3 slots, stride 262144
    unsigned short* __restrict__ bo)   // 3 slots, stride 512
{
    const int m = blockIdx.y;
    const float* W = (m == 0) ? Wq : (m == 1) ? Wk : Wv;
    const float* b = (m == 0) ? bq : (m == 1) ? bk : bv;
    if (blockIdx.x < 256) {
        const int idx = (blockIdx.x * 256 + threadIdx.x) * 4;
        float4 v = *(const float4*)&W[idx];
        ushort4v o;
        o[0] = f_to_bf16bits(v.x); o[1] = f_to_bf16bits(v.y);
        o[2] = f_to_bf16bits(v.z); o[3] = f_to_bf16bits(v.w);
        *(ushort4v*)&Wo[(size_t)m * 262144 + idx] = o;
    } else if (threadIdx.x < 128) {
        const int idx = threadIdx.x * 4;
        float4 v = *(const float4*)&b[idx];
        ushort4v o;
        o[0] = f_to_bf16bits(v.x); o[1] = f_to_bf16bits(v.y);
        o[2] = f_to_bf16bits(v.z); o[3] = f_to_bf16bits(v.w);
        *(ushort4v*)&bo[(size_t)m * 512 + idx] = o;
    }
}

// =====================================================================
// Projection: C[m,n] = sum_k X[m,k]*W[n,k] + b[n]. M=8192,N=512,K=512.
// grid (256,3): y = mode. 0: q (scaled), 1: k, 2: v (stored transposed).
// 128x128 tile, 4 waves 2x2 of 64x64, BK=64, 16x16x32 bf16 MFMA.
// =====================================================================
__global__ __launch_bounds__(256, 2) void proj_kernel(
    const unsigned short* __restrict__ Xall,  // 3 slots stride 4194304
    const unsigned short* __restrict__ Wall,  // 3 slots stride 262144
    const unsigned short* __restrict__ ball,  // 3 slots stride 512
    unsigned short* __restrict__ qbuf,        // [8192,512] pre-scaled
    unsigned short* __restrict__ kbuf,        // [8192,512]
    unsigned short* __restrict__ vTbuf,       // [2,512,4096]
    float qscale)
{
    __shared__ __align__(16) unsigned short Xs[128 * 64];
    __shared__ __align__(16) unsigned short Ws[128 * 64];

    const int mode = blockIdx.y;
    const unsigned short* X = Xall + (size_t)mode * 4194304;
    const unsigned short* W = Wall + (size_t)mode * 262144;
    const unsigned short* bias = ball + (size_t)mode * 512;

    const int tid = threadIdx.x;
    const int wave = tid >> 6, lane = tid & 63, quad = lane >> 4, l15 = lane & 15;
    const int m0 = (int)(blockIdx.x >> 2) << 7;
    const int n0 = (int)(blockIdx.x & 3) << 7;
    const int mw = (wave >> 1) << 6, nw = (wave & 1) << 6;

    floatx4 acc[4][4];
    #pragma unroll
    for (int i = 0; i < 4; i++)
        #pragma unroll
        for (int j = 0; j < 4; j++) acc[i][j] = floatx4{0.f, 0.f, 0.f, 0.f};

    for (int kt = 0; kt < 512; kt += 64) {
        #pragma unroll
        for (int i = 0; i < 4; i++) {
            const int r0 = wave * 32 + i * 8;
            gload_lds16(X + (size_t)(m0 + r0 + (lane >> 3)) * 512 + kt + (lane & 7) * 8, &Xs[r0 * 64]);
            gload_lds16(W + (size_t)(n0 + r0 + (lane >> 3)) * 512 + kt + (lane & 7) * 8, &Ws[r0 * 64]);
        }
        __syncthreads();
        #pragma unroll
        for (int kk = 0; kk < 64; kk += 32) {
            short8 a[4], b[4];
            #pragma unroll
            for (int i = 0; i < 4; i++) a[i] = *(const short8*)&Xs[(mw + 16 * i + l15) * 64 + kk + quad * 8];
            #pragma unroll
            for (int j = 0; j < 4; j++) b[j] = *(const short8*)&Ws[(nw + 16 * j + l15) * 64 + kk + quad * 8];
            #pragma unroll
            for (int i = 0; i < 4; i++)
                #pragma unroll
                for (int j = 0; j < 4; j++)
                    acc[i][j] = __builtin_amdgcn_mfma_f32_16x16x32_bf16(a[i], b[j], acc[i][j], 0, 0, 0);
        }
        __syncthreads();
    }

    float bfj[4];
    #pragma unroll
    for (int j = 0; j < 4; j++) bfj[j] = bf16bits_to_f(bias[n0 + nw + 16 * j + l15]);

    if (mode < 2) {
        unsigned short* out = (mode == 0) ? qbuf : kbuf;
        const float s = (mode == 0) ? qscale : 1.0f;
        #pragma unroll
        for (int i = 0; i < 4; i++) {
            const int mrow = m0 + mw + 16 * i + quad * 4;
            #pragma unroll
            for (int j = 0; j < 4; j++) {
                const int n = n0 + nw + 16 * j + l15;
                #pragma unroll
                for (int r = 0; r < 4; r++)
                    out[(size_t)(mrow + r) * 512 + n] = f_to_bf16bits((acc[i][j][r] + bfj[j]) * s);
            }
        }
    } else {
        #pragma unroll
        for (int i = 0; i < 4; i++) {
            const int mrow = m0 + mw + 16 * i + quad * 4;
            const int bb = mrow >> 12;
            const int s4 = mrow & 4095;
            #pragma unroll
            for (int j = 0; j < 4; j++) {
                const int n = n0 + nw + 16 * j + l15;
                ushort4v pk;
                #pragma unroll
                for (int r = 0; r < 4; r++) pk[r] = f_to_bf16bits(acc[i][j][r] + bfj[j]);
                *(ushort4v*)&vTbuf[((size_t)bb * 512 + n) * 4096 + s4] = pk;
            }
        }
    }
}

// =====================================================================
// K3: P = exp(q . k^T) for one 2048-key chunk, both batches.
// M=8192 (b,qrow), N=2048 (chunk-local key), K=512. grid 1024 (64 rb x 16 nb).
// Epilogue: bf16 P store + per-row denominator atomicAdd (f32).
// =====================================================================
__global__ __launch_bounds__(256, 2) void sgemm_exp_kernel(
    const unsigned short* __restrict__ Aq,   // [8192,512] q (pre-scaled)
    const unsigned short* __restrict__ Bk,   // [8192,512] k rows
    unsigned short* __restrict__ P,          // [8192,2048] chunk
    float* __restrict__ denom,               // [8192], pre-zeroed
    int coff)                                // chunk key offset within batch (0 or 2048)
{
    __shared__ __align__(16) unsigned short Xs[128 * 64];
    __shared__ __align__(16) unsigned short Ws[128 * 64];

    const int tid = threadIdx.x;
    const int wave = tid >> 6, lane = tid & 63, quad = lane >> 4, l15 = lane & 15;
    const int rb = blockIdx.x >> 4, nb = blockIdx.x & 15;
    const int m0 = rb << 7, n0 = nb << 7;
    const int bb = m0 >> 12;                 // batch of this row-block
    const int mw = (wave >> 1) << 6, nw = (wave & 1) << 6;

    const unsigned short* Brow = Bk + ((size_t)(bb << 12) + coff + n0) * 512;

    floatx4 acc[4][4];
    #pragma unroll
    for (int i = 0; i < 4; i++)
        #pragma unroll
        for (int j = 0; j < 4; j++) acc[i][j] = floatx4{0.f, 0.f, 0.f, 0.f};

    for (int kt = 0; kt < 512; kt += 64) {
        #pragma unroll
        for (int i = 0; i < 4; i++) {
            const int r0 = wave * 32 + i * 8;
            gload_lds16(Aq + (size_t)(m0 + r0 + (lane >> 3)) * 512 + kt + (lane & 7) * 8, &Xs[r0 * 64]);
            gload_lds16(Brow + (size_t)(r0 + (lane >> 3)) * 512 + kt + (lane & 7) * 8, &Ws[r0 * 64]);
        }
        __syncthreads();
        #pragma unroll
        for (int kk = 0; kk < 64; kk += 32) {
            short8 a[4], b[4];
            #pragma unroll
            for (int i = 0; i < 4; i++) a[i] = *(const short8*)&Xs[(mw + 16 * i + l15) * 64 + kk + quad * 8];
            #pragma unroll
            for (int j = 0; j < 4; j++) b[j] = *(const short8*)&Ws[(nw + 16 * j + l15) * 64 + kk + quad * 8];
            #pragma unroll
            for (int i = 0; i < 4; i++)
                #pragma unroll
                for (int j = 0; j < 4; j++)
                    acc[i][j] = __builtin_amdgcn_mfma_f32_16x16x32_bf16(a[i], b[j], acc[i][j], 0, 0, 0);
        }
        __syncthreads();
    }

    // epilogue: exp, bf16 store, denominator partials
    float rs[4][4];
    #pragma unroll
    for (int i = 0; i < 4; i++)
        #pragma unroll
        for (int r = 0; r < 4; r++) rs[i][r] = 0.f;

    #pragma unroll
    for (int i = 0; i < 4; i++) {
        const int mrow = m0 + mw + 16 * i + quad * 4;      // + r
        #pragma unroll
        for (int j = 0; j < 4; j++) {
            const int n = n0 + nw + 16 * j + l15;          // chunk-local col
            #pragma unroll
            for (int r = 0; r < 4; r++) {
                const float p = __expf(fminf(acc[i][j][r], 30.0f));
                const unsigned short pb = f_to_bf16bits(p);
                P[(size_t)(mrow + r) * 2048 + n] = pb;
                rs[i][r] += bf16bits_to_f(pb);
            }
        }
    }
    #pragma unroll
    for (int i = 0; i < 4; i++) {
        #pragma unroll
        for (int r = 0; r < 4; r++) {
            float v = rs[i][r];
            v += __shfl_xor(v, 1);
            v += __shfl_xor(v, 2);
            v += __shfl_xor(v, 4);
            v += __shfl_xor(v, 8);
            if (l15 == 0)
                atomicAdd(&denom[m0 + mw + 16 * i + quad * 4 + r], v);
        }
    }
}

// =====================================================================
// K4: numerator += P_chunk @ V. M=8192, N=512, K=2048 (split-K=2 -> 1024).
// grid 512 (64 rb x 4 nb x 2 ksplit). Epilogue: f32 atomicAdd into onum
// (= d_out, pre-zeroed).
// =====================================================================
__global__ __launch_bounds__(256, 2) void ogemm_kernel(
    const unsigned short* __restrict__ P,    // [8192,2048] chunk
    const unsigned short* __restrict__ vT,   // [2,512,4096]
    float* __restrict__ onum,                // [8192,512] f32
    int coff)
{
    __shared__ __align__(16) unsigned short Xs[128 * 64];
    __shared__ __align__(16) unsigned short Ws[128 * 64];

    const int tid = threadIdx.x;
    const int wave = tid >> 6, lane = tid & 63, quad = lane >> 4, l15 = lane & 15;
    const int rb = blockIdx.x >> 3;                 // 0..63
    const int nb = (blockIdx.x >> 1) & 3;           // 0..3
    const int kss = blockIdx.x & 1;                 // split-K half
    const int m0 = rb << 7, n0 = nb << 7;
    const int bb = m0 >> 12;
    const int mw = (wave >> 1) << 6, nw = (wave & 1) << 6;

    const unsigned short* Ab = P + (size_t)m0 * 2048 + (kss << 10);
    const unsigned short* Bb = vT + (size_t)bb * 2097152 + (size_t)n0 * 4096 + coff + (kss << 10);

    floatx4 acc[4][4];
    #pragma unroll
    for (int i = 0; i < 4; i++)
        #pragma unroll
        for (int j = 0; j < 4; j++) acc[i][j] = floatx4{0.f, 0.f, 0.f, 0.f};

    for (int kt = 0; kt < 1024; kt += 64) {
        #pragma unroll
        for (int i = 0; i < 4; i++) {
            const int r0 = wave * 32 + i * 8;
            gload_lds16(Ab + (size_t)(r0 + (lane >> 3)) * 2048 + kt + (lane & 7) * 8, &Xs[r0 * 64]);
            gload_lds16(Bb + (size_t)(r0 + (lane >> 3)) * 4096 + kt + (lane & 7) * 8, &Ws[r0 * 64]);
        }
        __syncthreads();
        #pragma unroll
        for (int kk = 0; kk < 64; kk += 32) {
            short8 a[4], b[4];
            #pragma unroll
            for (int i = 0; i < 4; i++) a[i] = *(const short8*)&Xs[(mw + 16 * i + l15) * 64 + kk + quad * 8];
            #pragma unroll
            for (int j = 0; j < 4; j++) b[j] = *(const short8*)&Ws[(nw + 16 * j + l15) * 64 + kk + quad * 8];
            #pragma unroll
            for (int i = 0; i < 4; i++)
                #pragma unroll
                for (int j = 0; j < 4; j++)
                    acc[i][j] = __builtin_amdgcn_mfma_f32_16x16x32_bf16(a[i], b[j], acc[i][j], 0, 0, 0);
        }
        __syncthreads();
    }

    #pragma unroll
    for (int i = 0; i < 4; i++) {
        const int mrow = m0 + mw + 16 * i + quad * 4;
        #pragma unroll
        for (int j = 0; j < 4; j++) {
            const int n = n0 + nw + 16 * j + l15;
            #pragma unroll
            for (int r = 0; r < 4; r++)
                atomicAdd(&onum[(size_t)(mrow + r) * 512 + n], acc[i][j][r]);
        }
    }
}

// =====================================================================
// Final: out = onum / denom (in place). grid 2048, 8 floats/thread.
// =====================================================================
__global__ __launch_bounds__(256) void divide_kernel(
    float* __restrict__ out, const float* __restrict__ denom)
{
    const int gid = blockIdx.x * 256 + threadIdx.x;
    const int row = gid >> 6;
    const int d0 = (gid & 63) << 3;
    const float inv = 1.0f / denom[row];
    float* p = out + (size_t)row * 512 + d0;
    float4 a = *(float4*)p;
    float4 b = *(float4*)(p + 4);
    a.x *= inv; a.y *= inv; a.z *= inv; a.w *= inv;
    b.x *= inv; b.y *= inv; b.z *= inv; b.w *= inv;
    *(float4*)p = a;
    *(float4*)(p + 4) = b;
}

// =====================================================================
extern "C" void kernel_launch(void* const* d_in, const int* in_sizes, int n_in,
                              void* d_out, int out_size, void* d_ws, size_t ws_size,
                              hipStream_t stream)
{
    (void)in_sizes; (void)n_in; (void)out_size; (void)ws_size;
    const float* Qin = (const float*)d_in[0];
    const float* Kin = (const float*)d_in[1];
    const float* Vin = (const float*)d_in[2];
    const float* Wq  = (const float*)d_in[3];
    const float* bq  = (const float*)d_in[4];
    const float* Wk  = (const float*)d_in[5];
    const float* bk  = (const float*)d_in[6];
    const float* Wv  = (const float*)d_in[7];
    const float* bv  = (const float*)d_in[8];

    const size_t M   = 4194304;    // 8192*512
    const size_t PCH = 16777216;   // 8192*2048
    const size_t WS_ = 262144;     // 512*512

    unsigned short* ws   = (unsigned short*)d_ws;
    unsigned short* A    = ws;            // conv Qc/Kc/Vc (3*M), later P-chunk (PCH)
    unsigned short* qs   = ws + PCH;
    unsigned short* ks   = qs + M;
    unsigned short* vT   = ks + M;
    unsigned short* Wc   = vT + M;        // 3 slots stride WS_
    unsigned short* bc   = Wc + 3 * WS_;  // 3 slots stride 512
    float* denom = (float*)(((uintptr_t)(bc + 3 * 512) + 15) & ~(uintptr_t)15);
    float* onum  = (float*)d_out;

    const float qscale = 1.0f / sqrtf(512.0f);

    // dtype conversion (fp32 -> bf16)
    conv_qkv_kernel<<<dim3(3 * 4096), dim3(256), 0, stream>>>(Qin, Kin, Vin, A);
    conv_wb_kernel<<<dim3(257, 3), dim3(256), 0, stream>>>(Wq, Wk, Wv, bq, bk, bv, Wc, bc);

    // zero accumulators
    hipMemsetAsync(denom, 0, 8192 * sizeof(float), stream);
    hipMemsetAsync(onum, 0, (size_t)8192 * 512 * sizeof(float), stream);

    // projections (one dispatch, 3 modes)
    proj_kernel<<<dim3(256, 3), dim3(256), 0, stream>>>(A, Wc, bc, qs, ks, vT, qscale);

    // attention as two GEMMs per 2048-key chunk
    for (int c = 0; c < 2; c++) {
        const int coff = c * 2048;
        sgemm_exp_kernel<<<dim3(1024), dim3(256), 0, stream>>>(qs, ks, A, denom, coff);
        ogemm_kernel<<<dim3(512), dim3(256), 0, stream>>>(A, vT, onum, coff);
    }

    divide_kernel<<<dim3(2048), dim3(256), 0, stream>>>(onum, denom);
}

// Round 4
// 286.702 us; speedup vs baseline: 1.0877x; 1.0877x over previous
//
#include <hip/hip_runtime.h>
#include <hip/hip_bf16.h>
#include <math.h>
#include <stdint.h>

// ---------- types ----------
typedef __attribute__((ext_vector_type(8))) short short8;     // 8 x bf16 (MFMA A/B frag)
typedef __attribute__((ext_vector_type(4))) float floatx4;    // MFMA C/D frag
typedef __attribute__((ext_vector_type(4))) unsigned short ushort4v;

// ---------- helpers ----------
__device__ __forceinline__ void gload_lds16(const void* g, void* lds) {
    __builtin_amdgcn_global_load_lds(
        (__attribute__((address_space(1))) void*)(g),
        (__attribute__((address_space(3))) void*)(lds), 16, 0, 0);
}
__device__ __forceinline__ float bf16bits_to_f(unsigned short u) {
    union { unsigned int i; float f; } x; x.i = ((unsigned int)u) << 16; return x.f;
}
__device__ __forceinline__ unsigned short f_to_bf16bits(float f) {
    union { float f; unsigned int i; } x; x.f = f;
    unsigned int lsb = (x.i >> 16) & 1u;
    x.i += 0x7fffu + lsb;                      // round-to-nearest-even
    return (unsigned short)(x.i >> 16);
}
__device__ __forceinline__ ushort4v cvt4(float4 v) {
    ushort4v o;
    o[0] = f_to_bf16bits(v.x); o[1] = f_to_bf16bits(v.y);
    o[2] = f_to_bf16bits(v.z); o[3] = f_to_bf16bits(v.w);
    return o;
}

// =====================================================================
// Fused conversion + projection: C[m,n] = sum_k X[m,k]*W[n,k] + b[n].
// X,W,b are fp32 (converted to bf16 in-register during staging).
// M=8192, N=512, K=512. grid (256,3): y = mode (0:q scaled, 1:k, 2:v->vT).
// 128x128 tile, 4 waves 2x2 of 64x64, BK=64, 16x16x32 bf16 MFMA.
// =====================================================================
__global__ __launch_bounds__(256, 2) void proj_fused_kernel(
    const float* __restrict__ Qin, const float* __restrict__ Kin, const float* __restrict__ Vin,
    const float* __restrict__ Wq, const float* __restrict__ bq,
    const float* __restrict__ Wk, const float* __restrict__ bk,
    const float* __restrict__ Wv, const float* __restrict__ bv,
    unsigned short* __restrict__ qbuf,        // [8192,512] pre-scaled by 1/sqrt(512)
    unsigned short* __restrict__ kbuf,        // [8192,512]
    unsigned short* __restrict__ vTbuf,       // [2,512,4096]
    float qscale)
{
    __shared__ __align__(16) unsigned short Xs[128 * 64];
    __shared__ __align__(16) unsigned short Ws[128 * 64];

    const int mode = blockIdx.y;
    const float* X    = (mode == 0) ? Qin : (mode == 1) ? Kin : Vin;
    const float* W    = (mode == 0) ? Wq  : (mode == 1) ? Wk  : Wv;
    const float* bias = (mode == 0) ? bq  : (mode == 1) ? bk  : bv;

    const int tid = threadIdx.x;
    const int wave = tid >> 6, lane = tid & 63, quad = lane >> 4, l15 = lane & 15;
    const int m0 = (int)(blockIdx.x >> 2) << 7;
    const int n0 = (int)(blockIdx.x & 3) << 7;
    const int mw = (wave >> 1) << 6, nw = (wave & 1) << 6;

    // staging assignment: thread -> (row = tid>>1, seg = tid&1); 8 float4 per tile
    const int srow = tid >> 1, sseg = tid & 1;
    const float* xrow = X + (size_t)(m0 + srow) * 512 + sseg * 32;
    const float* wrow = W + (size_t)(n0 + srow) * 512 + sseg * 32;
    unsigned short* xls = &Xs[srow * 64 + sseg * 32];
    unsigned short* wls = &Ws[srow * 64 + sseg * 32];

    floatx4 acc[4][4];
    #pragma unroll
    for (int i = 0; i < 4; i++)
        #pragma unroll
        for (int j = 0; j < 4; j++) acc[i][j] = floatx4{0.f, 0.f, 0.f, 0.f};

    for (int kt = 0; kt < 512; kt += 64) {
        float4 xv[8], wv[8];
        #pragma unroll
        for (int i = 0; i < 8; i++) {
            xv[i] = *(const float4*)(xrow + kt + i * 4);
            wv[i] = *(const float4*)(wrow + kt + i * 4);
        }
        __syncthreads();               // previous tile fully consumed
        #pragma unroll
        for (int i = 0; i < 8; i++) {
            *(ushort4v*)(xls + i * 4) = cvt4(xv[i]);
            *(ushort4v*)(wls + i * 4) = cvt4(wv[i]);
        }
        __syncthreads();
        #pragma unroll
        for (int kk = 0; kk < 64; kk += 32) {
            short8 a[4], b[4];
            #pragma unroll
            for (int i = 0; i < 4; i++) a[i] = *(const short8*)&Xs[(mw + 16 * i + l15) * 64 + kk + quad * 8];
            #pragma unroll
            for (int j = 0; j < 4; j++) b[j] = *(const short8*)&Ws[(nw + 16 * j + l15) * 64 + kk + quad * 8];
            #pragma unroll
            for (int i = 0; i < 4; i++)
                #pragma unroll
                for (int j = 0; j < 4; j++)
                    acc[i][j] = __builtin_amdgcn_mfma_f32_16x16x32_bf16(a[i], b[j], acc[i][j], 0, 0, 0);
        }
    }

    float bfj[4];
    #pragma unroll
    for (int j = 0; j < 4; j++) bfj[j] = bias[n0 + nw + 16 * j + l15];

    if (mode < 2) {
        unsigned short* out = (mode == 0) ? qbuf : kbuf;
        const float s = (mode == 0) ? qscale : 1.0f;
        #pragma unroll
        for (int i = 0; i < 4; i++) {
            const int mrow = m0 + mw + 16 * i + quad * 4;   // C/D: row = quad*4+reg
            #pragma unroll
            for (int j = 0; j < 4; j++) {
                const int n = n0 + nw + 16 * j + l15;       // C/D: col = lane&15
                #pragma unroll
                for (int r = 0; r < 4; r++)
                    out[(size_t)(mrow + r) * 512 + n] = f_to_bf16bits((acc[i][j][r] + bfj[j]) * s);
            }
        }
    } else {
        // v: store transposed vT[b][e][s]; 4 consecutive s per lane -> 8B store
        #pragma unroll
        for (int i = 0; i < 4; i++) {
            const int mrow = m0 + mw + 16 * i + quad * 4;
            const int bb = mrow >> 12;
            const int s4 = mrow & 4095;
            #pragma unroll
            for (int j = 0; j < 4; j++) {
                const int n = n0 + nw + 16 * j + l15;
                ushort4v pk;
                #pragma unroll
                for (int r = 0; r < 4; r++) pk[r] = f_to_bf16bits(acc[i][j][r] + bfj[j]);
                *(ushort4v*)&vTbuf[((size_t)bb * 512 + n) * 4096 + s4] = pk;
            }
        }
    }
}

// =====================================================================
// Flash attention (no max-subtraction: logits ~N(0,1); clamp 30 as insurance).
// WG = 256 threads (4 waves), BQ=64 q-rows, TK=32 keys/tile, key-split NSPLIT.
// S-phase: wave w owns q-rows 16w..16w+15 (Q frags in regs, K-tile from LDS).
// P -> LDS (layout transform C->A). PV-phase: wave w owns d-cols 128w..128w+127.
// =====================================================================
template <int NSPLIT>
__global__ __launch_bounds__(256, 2) void attn_kernel(
    const unsigned short* __restrict__ q,    // [8192,512] pre-scaled
    const unsigned short* __restrict__ k,    // [8192,512]
    const unsigned short* __restrict__ vT,   // [2,512,4096]
    unsigned short* __restrict__ num,        // [NSPLIT,8192,512] bf16 partial numerators
    float* __restrict__ denom)               // [NSPLIT,8192]
{
    constexpr int TK  = 32;
    constexpr int KST = 520;   // 512 + 8 pad
    constexpr int PST = 40;    // 32 + 8 pad
    __shared__ __align__(16) unsigned short Ks [TK * KST];   // 33.3 KB
    __shared__ __align__(16) unsigned short Vts[512 * TK];   // 32 KB
    __shared__ __align__(16) unsigned short Ps [64 * PST];   // 5 KB

    const int tid = threadIdx.x;
    const int wave = tid >> 6, lane = tid & 63, quad = lane >> 4, l15 = lane & 15;
    const int bid = blockIdx.x;
    const int sp   = bid & (NSPLIT - 1);
    const int qblk = bid / NSPLIT;
    const int bb = qblk >> 6;              // batch
    const int q0 = (qblk & 63) << 6;       // q-tile start within batch
    const size_t rowbase = (size_t)bb * 4096 + q0;

    // Q fragments for this wave's 16 rows: A[m=lane&15][k=quad*8+j], 16 k-steps
    short8 qf[16];
    {
        const unsigned short* qrow = q + (rowbase + 16 * wave + l15) * 512;
        #pragma unroll
        for (int t = 0; t < 16; t++) qf[t] = *(const short8*)&qrow[t * 32 + quad * 8];
    }

    floatx4 oacc[4][8];                    // rows 16i+quad*4+r, cols 128*wave+16c+l15
    #pragma unroll
    for (int i = 0; i < 4; i++)
        #pragma unroll
        for (int c = 0; c < 8; c++) oacc[i][c] = floatx4{0.f, 0.f, 0.f, 0.f};
    float dsum[4] = {0.f, 0.f, 0.f, 0.f};

    const unsigned short* kb = k  + (size_t)bb * 4096 * 512;
    const unsigned short* vb = vT + (size_t)bb * 512 * 4096;

    const int jbeg = sp * (4096 / NSPLIT);
    const int jend = jbeg + (4096 / NSPLIT);
    for (int j0 = jbeg; j0 < jend; j0 += TK) {
        // --- stage K tile (32 rows x 512) and Vt tile (512 rows x 32), async ---
        #pragma unroll
        for (int r = 0; r < 8; r++) {
            const int row = wave * 8 + r;                       // one 1KB row per issue
            gload_lds16(kb + (size_t)(j0 + row) * 512 + lane * 8, &Ks[row * KST]);
        }
        #pragma unroll
        for (int i2 = 0; i2 < 8; i2++) {
            const int dd0 = (wave * 8 + i2) * 16;               // 16 d-rows x 64B per issue
            gload_lds16(vb + (size_t)(dd0 + (lane >> 2)) * 4096 + j0 + (lane & 3) * 8,
                        &Vts[dd0 * TK]);
        }
        __syncthreads();

        // --- S = q . K^T for this wave's 16 rows x 32 keys ---
        floatx4 sA[2], sB[2];
        sA[0] = sA[1] = sB[0] = sB[1] = floatx4{0.f, 0.f, 0.f, 0.f};
        #pragma unroll
        for (int t = 0; t < 16; t += 2) {
            #pragma unroll
            for (int c = 0; c < 2; c++) {
                short8 b0 = *(const short8*)&Ks[(c * 16 + l15) * KST + t * 32 + quad * 8];
                sA[c] = __builtin_amdgcn_mfma_f32_16x16x32_bf16(qf[t], b0, sA[c], 0, 0, 0);
                short8 b1 = *(const short8*)&Ks[(c * 16 + l15) * KST + (t + 1) * 32 + quad * 8];
                sB[c] = __builtin_amdgcn_mfma_f32_16x16x32_bf16(qf[t + 1], b1, sB[c], 0, 0, 0);
            }
        }
        // --- P = exp(S); accumulate denom with the bf16-rounded value ---
        #pragma unroll
        for (int c = 0; c < 2; c++) {
            #pragma unroll
            for (int r = 0; r < 4; r++) {
                const float p = __expf(fminf(sA[c][r] + sB[c][r], 30.0f));
                const unsigned short pb = f_to_bf16bits(p);
                dsum[r] += bf16bits_to_f(pb);
                Ps[(16 * wave + quad * 4 + r) * PST + c * 16 + l15] = pb;
            }
        }
        __syncthreads();   // P written by all waves before cross-wave A-frag reads

        // --- O[0:64][128w:128w+128] += P @ V ---
        short8 ap[4];
        #pragma unroll
        for (int i = 0; i < 4; i++) ap[i] = *(const short8*)&Ps[(16 * i + l15) * PST + quad * 8];
        #pragma unroll
        for (int c = 0; c < 8; c++) {
            short8 bvf = *(const short8*)&Vts[(128 * wave + 16 * c + l15) * TK + quad * 8];
            #pragma unroll
            for (int i = 0; i < 4; i++)
                oacc[i][c] = __builtin_amdgcn_mfma_f32_16x16x32_bf16(ap[i], bvf, oacc[i][c], 0, 0, 0);
        }
        __syncthreads();   // protect Ks/Vts before next stage
    }

    // row-sum the per-lane denominator partials
    #pragma unroll
    for (int r = 0; r < 4; r++) {
        float v = dsum[r];
        v += __shfl_xor(v, 1);
        v += __shfl_xor(v, 2);
        v += __shfl_xor(v, 4);
        v += __shfl_xor(v, 8);
        dsum[r] = v;
    }
    if (l15 == 0) {
        #pragma unroll
        for (int r = 0; r < 4; r++)
            denom[(size_t)sp * 8192 + rowbase + 16 * wave + quad * 4 + r] = dsum[r];
    }

    // store bf16 numerator partials
    #pragma unroll
    for (int i = 0; i < 4; i++) {
        #pragma unroll
        for (int r = 0; r < 4; r++) {
            const size_t row = rowbase + 16 * i + quad * 4 + r;
            unsigned short* np_ = num + ((size_t)sp * 8192 + row) * 512 + 128 * wave + l15;
            #pragma unroll
            for (int c = 0; c < 8; c++)
                np_[16 * c] = f_to_bf16bits(oacc[i][c][r]);
        }
    }
}

// =====================================================================
// Combine: out = (sum_sp num) / (sum_sp denom), fp32 out. 8 elems/thread.
// =====================================================================
__global__ __launch_bounds__(256) void combine_kernel(
    const unsigned short* __restrict__ num,
    const float* __restrict__ denom,
    float* __restrict__ out,
    int nsplit)
{
    const int gid = blockIdx.x * 256 + threadIdx.x;
    const int srow = gid >> 6;            // 0..8191
    const int d0 = (gid & 63) << 3;       // 0..504 step 8
    float s[8];
    #pragma unroll
    for (int e = 0; e < 8; e++) s[e] = 0.f;
    float den = 0.f;
    for (int sp = 0; sp < nsplit; sp++) {
        den += denom[(size_t)sp * 8192 + srow];
        short8 v = *(const short8*)(num + ((size_t)sp * 8192 + srow) * 512 + d0);
        #pragma unroll
        for (int e = 0; e < 8; e++) s[e] += bf16bits_to_f((unsigned short)v[e]);
    }
    const float inv = 1.0f / den;
    float4 o0, o1;
    o0.x = s[0] * inv; o0.y = s[1] * inv; o0.z = s[2] * inv; o0.w = s[3] * inv;
    o1.x = s[4] * inv; o1.y = s[5] * inv; o1.z = s[6] * inv; o1.w = s[7] * inv;
    float* op = out + (size_t)srow * 512 + d0;
    *(float4*)op = o0;
    *(float4*)(op + 4) = o1;
}

// =====================================================================
extern "C" void kernel_launch(void* const* d_in, const int* in_sizes, int n_in,
                              void* d_out, int out_size, void* d_ws, size_t ws_size,
                              hipStream_t stream)
{
    (void)in_sizes; (void)n_in; (void)out_size;
    const float* Qin = (const float*)d_in[0];
    const float* Kin = (const float*)d_in[1];
    const float* Vin = (const float*)d_in[2];
    const float* Wq  = (const float*)d_in[3];
    const float* bq  = (const float*)d_in[4];
    const float* Wk  = (const float*)d_in[5];
    const float* bk  = (const float*)d_in[6];
    const float* Wv  = (const float*)d_in[7];
    const float* bv  = (const float*)d_in[8];

    const size_t M = (size_t)8192 * 512;     // 4,194,304 elements

    // tier by ws size: numb (nsplit*M) + qs/ks/vT (3*M) bf16 + denom (nsplit*8192 f32)
    auto need = [&](size_t ns) -> size_t {
        return ((size_t)ns + 3) * M * 2 + (size_t)ns * 8192 * 4 + 64;
    };
    const int nsplit = (ws_size >= need(4)) ? 4 : (ws_size >= need(2)) ? 2 : 1;

    unsigned short* ws   = (unsigned short*)d_ws;
    unsigned short* numb = ws;                           // nsplit * M
    unsigned short* qs   = ws + (size_t)nsplit * M;
    unsigned short* ks   = qs + M;
    unsigned short* vT   = ks + M;
    float* denom = (float*)(((uintptr_t)(vT + M) + 15) & ~(uintptr_t)15);

    const float qscale = 1.0f / sqrtf(512.0f);

    // fused conversion + projections (one dispatch, 3 modes)
    proj_fused_kernel<<<dim3(256, 3), dim3(256), 0, stream>>>(
        Qin, Kin, Vin, Wq, bq, Wk, bk, Wv, bv, qs, ks, vT, qscale);

    // fused flash attention with key-split
    if (nsplit == 4)
        attn_kernel<4><<<dim3(512), dim3(256), 0, stream>>>(qs, ks, vT, numb, denom);
    else if (nsplit == 2)
        attn_kernel<2><<<dim3(256), dim3(256), 0, stream>>>(qs, ks, vT, numb, denom);
    else
        attn_kernel<1><<<dim3(128), dim3(256), 0, stream>>>(qs, ks, vT, numb, denom);

    combine_kernel<<<dim3(2048), dim3(256), 0, stream>>>(
        numb, denom, (float*)d_out, nsplit);
}

// Round 5
// 259.928 us; speedup vs baseline: 1.1997x; 1.1030x over previous
//
#include <hip/hip_runtime.h>
#include <hip/hip_bf16.h>
#include <math.h>
#include <stdint.h>

// ---------- types ----------
typedef __attribute__((ext_vector_type(8))) short short8;     // 8 x bf16 (MFMA A/B frag)
typedef __attribute__((ext_vector_type(4))) float floatx4;    // MFMA C/D frag
typedef __attribute__((ext_vector_type(4))) unsigned short ushort4v;

// ---------- helpers ----------
__device__ __forceinline__ void gload_lds16(const void* g, void* lds) {
    __builtin_amdgcn_global_load_lds(
        (__attribute__((address_space(1))) void*)(g),
        (__attribute__((address_space(3))) void*)(lds), 16, 0, 0);
}
__device__ __forceinline__ float bf16bits_to_f(unsigned short u) {
    union { unsigned int i; float f; } x; x.i = ((unsigned int)u) << 16; return x.f;
}
__device__ __forceinline__ unsigned short f_to_bf16bits(float f) {
    union { float f; unsigned int i; } x; x.f = f;
    unsigned int lsb = (x.i >> 16) & 1u;
    x.i += 0x7fffu + lsb;                      // round-to-nearest-even
    return (unsigned short)(x.i >> 16);
}

// =====================================================================
// fp32 -> bf16: Q,K,V inputs in one dispatch. grid 3*4096, 4 elems/thread.
// =====================================================================
__global__ __launch_bounds__(256) void conv_qkv_kernel(
    const float* __restrict__ Q, const float* __restrict__ K, const float* __restrict__ V,
    unsigned short* __restrict__ out)   // 3 slots, stride 4194304
{
    const int seg = blockIdx.x >> 12;            // /4096
    const int blk = blockIdx.x & 4095;
    const float* src = (seg == 0) ? Q : (seg == 1) ? K : V;
    const int idx = (blk * 256 + threadIdx.x) * 4;
    float4 v = *(const float4*)&src[idx];
    ushort4v o;
    o[0] = f_to_bf16bits(v.x); o[1] = f_to_bf16bits(v.y);
    o[2] = f_to_bf16bits(v.z); o[3] = f_to_bf16bits(v.w);
    *(ushort4v*)&out[(size_t)seg * 4194304 + idx] = o;
}

// single-input fp32 -> bf16 (small-ws fallback). grid 4096.
__global__ __launch_bounds__(256) void conv1_kernel(
    const float* __restrict__ in, unsigned short* __restrict__ out)
{
    const int idx = (blockIdx.x * 256 + threadIdx.x) * 4;
    float4 v = *(const float4*)&in[idx];
    ushort4v o;
    o[0] = f_to_bf16bits(v.x); o[1] = f_to_bf16bits(v.y);
    o[2] = f_to_bf16bits(v.z); o[3] = f_to_bf16bits(v.w);
    *(ushort4v*)&out[idx] = o;
}

// W[512x512] x3 and b[512] x3 -> bf16 slots. grid (257, 3).
__global__ __launch_bounds__(256) void conv_wb_kernel(
    const float* __restrict__ Wq, const float* __restrict__ Wk, const float* __restrict__ Wv,
    const float* __restrict__ bq, const float* __restrict__ bk, const float* __restrict__ bv,
    unsigned short* __restrict__ Wo,   // 3 slots, stride 262144
    unsigned short* __restrict__ bo)   // 3 slots, stride 512
{
    const int m = blockIdx.y;
    const float* W = (m == 0) ? Wq : (m == 1) ? Wk : Wv;
    const float* b = (m == 0) ? bq : (m == 1) ? bk : bv;
    if (blockIdx.x < 256) {
        const int idx = (blockIdx.x * 256 + threadIdx.x) * 4;
        float4 v = *(const float4*)&W[idx];
        ushort4v o;
        o[0] = f_to_bf16bits(v.x); o[1] = f_to_bf16bits(v.y);
        o[2] = f_to_bf16bits(v.z); o[3] = f_to_bf16bits(v.w);
        *(ushort4v*)&Wo[(size_t)m * 262144 + idx] = o;
    } else if (threadIdx.x < 128) {
        const int idx = threadIdx.x * 4;
        float4 v = *(const float4*)&b[idx];
        ushort4v o;
        o[0] = f_to_bf16bits(v.x); o[1] = f_to_bf16bits(v.y);
        o[2] = f_to_bf16bits(v.z); o[3] = f_to_bf16bits(v.w);
        *(ushort4v*)&bo[(size_t)m * 512 + idx] = o;
    }
}

// =====================================================================
// Projection: C[m,n] = sum_k X[m,k]*W[n,k] + b[n]. M=8192,N=512,K=512.
// grid (256, nmodes); mode = mode_base + blockIdx.y; X = Xall + y*xstride.
// 0: q (scaled), 1: k, 2: v (stored transposed). 128x128 tile, BK=64.
// =====================================================================
__global__ __launch_bounds__(256, 2) void proj_kernel(
    const unsigned short* __restrict__ Xall,
    size_t xstride, int mode_base,
    const unsigned short* __restrict__ Wall,  // 3 slots stride 262144
    const unsigned short* __restrict__ ball,  // 3 slots stride 512
    unsigned short* __restrict__ qbuf,        // [8192,512] pre-scaled
    unsigned short* __restrict__ kbuf,        // [8192,512]
    unsigned short* __restrict__ vTbuf,       // [2,512,4096]
    float qscale)
{
    __shared__ __align__(16) unsigned short Xs[128 * 64];
    __shared__ __align__(16) unsigned short Ws[128 * 64];

    const int mode = mode_base + blockIdx.y;
    const unsigned short* X = Xall + (size_t)blockIdx.y * xstride;
    const unsigned short* W = Wall + (size_t)mode * 262144;
    const unsigned short* bias = ball + (size_t)mode * 512;

    const int tid = threadIdx.x;
    const int wave = tid >> 6, lane = tid & 63, quad = lane >> 4, l15 = lane & 15;
    const int m0 = (int)(blockIdx.x >> 2) << 7;
    const int n0 = (int)(blockIdx.x & 3) << 7;
    const int mw = (wave >> 1) << 6, nw = (wave & 1) << 6;

    floatx4 acc[4][4];
    #pragma unroll
    for (int i = 0; i < 4; i++)
        #pragma unroll
        for (int j = 0; j < 4; j++) acc[i][j] = floatx4{0.f, 0.f, 0.f, 0.f};

    for (int kt = 0; kt < 512; kt += 64) {
        #pragma unroll
        for (int i = 0; i < 4; i++) {
            const int r0 = wave * 32 + i * 8;
            gload_lds16(X + (size_t)(m0 + r0 + (lane >> 3)) * 512 + kt + (lane & 7) * 8, &Xs[r0 * 64]);
            gload_lds16(W + (size_t)(n0 + r0 + (lane >> 3)) * 512 + kt + (lane & 7) * 8, &Ws[r0 * 64]);
        }
        __syncthreads();
        #pragma unroll
        for (int kk = 0; kk < 64; kk += 32) {
            short8 a[4], b[4];
            #pragma unroll
            for (int i = 0; i < 4; i++) a[i] = *(const short8*)&Xs[(mw + 16 * i + l15) * 64 + kk + quad * 8];
            #pragma unroll
            for (int j = 0; j < 4; j++) b[j] = *(const short8*)&Ws[(nw + 16 * j + l15) * 64 + kk + quad * 8];
            #pragma unroll
            for (int i = 0; i < 4; i++)
                #pragma unroll
                for (int j = 0; j < 4; j++)
                    acc[i][j] = __builtin_amdgcn_mfma_f32_16x16x32_bf16(a[i], b[j], acc[i][j], 0, 0, 0);
        }
        __syncthreads();
    }

    float bfj[4];
    #pragma unroll
    for (int j = 0; j < 4; j++) bfj[j] = bf16bits_to_f(bias[n0 + nw + 16 * j + l15]);

    if (mode < 2) {
        unsigned short* out = (mode == 0) ? qbuf : kbuf;
        const float s = (mode == 0) ? qscale : 1.0f;
        #pragma unroll
        for (int i = 0; i < 4; i++) {
            const int mrow = m0 + mw + 16 * i + quad * 4;   // C/D: row = quad*4+reg
            #pragma unroll
            for (int j = 0; j < 4; j++) {
                const int n = n0 + nw + 16 * j + l15;       // C/D: col = lane&15
                #pragma unroll
                for (int r = 0; r < 4; r++)
                    out[(size_t)(mrow + r) * 512 + n] = f_to_bf16bits((acc[i][j][r] + bfj[j]) * s);
            }
        }
    } else {
        #pragma unroll
        for (int i = 0; i < 4; i++) {
            const int mrow = m0 + mw + 16 * i + quad * 4;
            const int bb = mrow >> 12;
            const int s4 = mrow & 4095;
            #pragma unroll
            for (int j = 0; j < 4; j++) {
                const int n = n0 + nw + 16 * j + l15;
                ushort4v pk;
                #pragma unroll
                for (int r = 0; r < 4; r++) pk[r] = f_to_bf16bits(acc[i][j][r] + bfj[j]);
                *(ushort4v*)&vTbuf[((size_t)bb * 512 + n) * 4096 + s4] = pk;
            }
        }
    }
}

// =====================================================================
// Flash attention v2: V fragments direct global->reg (no V LDS), 2 barriers
// per key-tile. WG = 4 waves, BQ=64 q-rows, TK=32 keys, key-split NSPLIT.
// S-phase: wave owns 16 q-rows (Q frags in regs, K from LDS).
// PV-phase: wave owns d-cols [128w,128w+128), V frags prefetched during S.
// LDS = Ks 33.3 KB + Ps 5 KB = 38.3 KB -> up to 4 WGs/CU.
// =====================================================================
template <int NSPLIT>
__global__ __launch_bounds__(256, 2) void attn_kernel(
    const unsigned short* __restrict__ q,    // [8192,512] pre-scaled
    const unsigned short* __restrict__ k,    // [8192,512]
    const unsigned short* __restrict__ vT,   // [2,512,4096]
    unsigned short* __restrict__ num,        // [NSPLIT,8192,512] bf16 partial numerators
    float* __restrict__ denom)               // [NSPLIT,8192]
{
    constexpr int TK  = 32;
    constexpr int KST = 520;   // 512 + 8 pad
    constexpr int PST = 40;    // 32 + 8 pad
    __shared__ __align__(16) unsigned short Ks[TK * KST];   // 33.3 KB
    __shared__ __align__(16) unsigned short Ps[64 * PST];   // 5 KB

    const int tid = threadIdx.x;
    const int wave = tid >> 6, lane = tid & 63, quad = lane >> 4, l15 = lane & 15;
    const int bid = blockIdx.x;
    const int sp   = bid & (NSPLIT - 1);
    const int qblk = bid / NSPLIT;
    const int bb = qblk >> 6;              // batch
    const int q0 = (qblk & 63) << 6;       // q-tile start within batch
    const size_t rowbase = (size_t)bb * 4096 + q0;

    // Q fragments for this wave's 16 rows: A[m=lane&15][k=quad*8+j], 16 k-steps
    short8 qf[16];
    {
        const unsigned short* qrow = q + (rowbase + 16 * wave + l15) * 512;
        #pragma unroll
        for (int t = 0; t < 16; t++) qf[t] = *(const short8*)&qrow[t * 32 + quad * 8];
    }

    floatx4 oacc[4][8];                    // rows 16i+quad*4+r, cols 128*wave+16c+l15
    #pragma unroll
    for (int i = 0; i < 4; i++)
        #pragma unroll
        for (int c = 0; c < 8; c++) oacc[i][c] = floatx4{0.f, 0.f, 0.f, 0.f};
    float dsum[4] = {0.f, 0.f, 0.f, 0.f};

    const unsigned short* kb = k  + (size_t)bb * 4096 * 512;
    // per-lane V base: row (128*wave + l15) of vT, key-chunk quad*8
    const unsigned short* vrow = vT + (size_t)bb * 512 * 4096
                               + (size_t)(128 * wave + l15) * 4096 + quad * 8;

    const int jbeg = sp * (4096 / NSPLIT);
    const int jend = jbeg + (4096 / NSPLIT);
    for (int j0 = jbeg; j0 < jend; j0 += TK) {
        // --- stage K tile (32 rows x 512) async; V stays in global ---
        #pragma unroll
        for (int r = 0; r < 8; r++) {
            const int row = wave * 8 + r;                       // one 1KB row per issue
            gload_lds16(kb + (size_t)(j0 + row) * 512 + lane * 8, &Ks[row * KST]);
        }
        __syncthreads();   // B1: K staged

        // --- prefetch this wave's V fragments (land during S-phase) ---
        short8 vf[8];
        #pragma unroll
        for (int c = 0; c < 8; c++)
            vf[c] = *(const short8*)&vrow[(size_t)c * 16 * 4096 + j0];

        // --- S = q . K^T for this wave's 16 rows x 32 keys ---
        floatx4 sA[2], sB[2];
        sA[0] = sA[1] = sB[0] = sB[1] = floatx4{0.f, 0.f, 0.f, 0.f};
        #pragma unroll
        for (int t = 0; t < 16; t += 2) {
            #pragma unroll
            for (int c = 0; c < 2; c++) {
                short8 b0 = *(const short8*)&Ks[(c * 16 + l15) * KST + t * 32 + quad * 8];
                sA[c] = __builtin_amdgcn_mfma_f32_16x16x32_bf16(qf[t], b0, sA[c], 0, 0, 0);
                short8 b1 = *(const short8*)&Ks[(c * 16 + l15) * KST + (t + 1) * 32 + quad * 8];
                sB[c] = __builtin_amdgcn_mfma_f32_16x16x32_bf16(qf[t + 1], b1, sB[c], 0, 0, 0);
            }
        }
        // --- P = exp(S); accumulate denom with the bf16-rounded value ---
        #pragma unroll
        for (int c = 0; c < 2; c++) {
            #pragma unroll
            for (int r = 0; r < 4; r++) {
                const float p = __expf(fminf(sA[c][r] + sB[c][r], 30.0f));
                const unsigned short pb = f_to_bf16bits(p);
                dsum[r] += bf16bits_to_f(pb);
                Ps[(16 * wave + quad * 4 + r) * PST + c * 16 + l15] = pb;
            }
        }
        __syncthreads();   // B2: P complete before cross-wave A-frag reads

        // --- O[0:64][128w:128w+128] += P @ V (A from LDS, B from regs) ---
        // NOTE: no barrier after PV — next iter's B1 already orders PV reads
        // of Ps against the next P writes, and S-reads of Ks finished pre-B2.
        short8 ap[4];
        #pragma unroll
        for (int i = 0; i < 4; i++) ap[i] = *(const short8*)&Ps[(16 * i + l15) * PST + quad * 8];
        #pragma unroll
        for (int c = 0; c < 8; c++) {
            #pragma unroll
            for (int i = 0; i < 4; i++)
                oacc[i][c] = __builtin_amdgcn_mfma_f32_16x16x32_bf16(ap[i], vf[c], oacc[i][c], 0, 0, 0);
        }
    }

    // row-sum the per-lane denominator partials
    #pragma unroll
    for (int r = 0; r < 4; r++) {
        float v = dsum[r];
        v += __shfl_xor(v, 1);
        v += __shfl_xor(v, 2);
        v += __shfl_xor(v, 4);
        v += __shfl_xor(v, 8);
        dsum[r] = v;
    }
    if (l15 == 0) {
        #pragma unroll
        for (int r = 0; r < 4; r++)
            denom[(size_t)sp * 8192 + rowbase + 16 * wave + quad * 4 + r] = dsum[r];
    }

    // store bf16 numerator partials
    #pragma unroll
    for (int i = 0; i < 4; i++) {
        #pragma unroll
        for (int r = 0; r < 4; r++) {
            const size_t row = rowbase + 16 * i + quad * 4 + r;
            unsigned short* np_ = num + ((size_t)sp * 8192 + row) * 512 + 128 * wave + l15;
            #pragma unroll
            for (int c = 0; c < 8; c++)
                np_[16 * c] = f_to_bf16bits(oacc[i][c][r]);
        }
    }
}

// =====================================================================
// Combine: out = (sum_sp num) / (sum_sp denom), fp32 out. 8 elems/thread.
// =====================================================================
__global__ __launch_bounds__(256) void combine_kernel(
    const unsigned short* __restrict__ num,
    const float* __restrict__ denom,
    float* __restrict__ out,
    int nsplit)
{
    const int gid = blockIdx.x * 256 + threadIdx.x;
    const int srow = gid >> 6;            // 0..8191
    const int d0 = (gid & 63) << 3;       // 0..504 step 8
    float s[8];
    #pragma unroll
    for (int e = 0; e < 8; e++) s[e] = 0.f;
    float den = 0.f;
    for (int sp = 0; sp < nsplit; sp++) {
        den += denom[(size_t)sp * 8192 + srow];
        short8 v = *(const short8*)(num + ((size_t)sp * 8192 + srow) * 512 + d0);
        #pragma unroll
        for (int e = 0; e < 8; e++) s[e] += bf16bits_to_f((unsigned short)v[e]);
    }
    const float inv = 1.0f / den;
    float4 o0, o1;
    o0.x = s[0] * inv; o0.y = s[1] * inv; o0.z = s[2] * inv; o0.w = s[3] * inv;
    o1.x = s[4] * inv; o1.y = s[5] * inv; o1.z = s[6] * inv; o1.w = s[7] * inv;
    float* op = out + (size_t)srow * 512 + d0;
    *(float4*)op = o0;
    *(float4*)(op + 4) = o1;
}

// =====================================================================
extern "C" void kernel_launch(void* const* d_in, const int* in_sizes, int n_in,
                              void* d_out, int out_size, void* d_ws, size_t ws_size,
                              hipStream_t stream)
{
    (void)in_sizes; (void)n_in; (void)out_size;
    const float* Qin = (const float*)d_in[0];
    const float* Kin = (const float*)d_in[1];
    const float* Vin = (const float*)d_in[2];
    const float* Wq  = (const float*)d_in[3];
    const float* bq  = (const float*)d_in[4];
    const float* Wk  = (const float*)d_in[5];
    const float* bk  = (const float*)d_in[6];
    const float* Wv  = (const float*)d_in[7];
    const float* bv  = (const float*)d_in[8];

    const size_t M   = (size_t)8192 * 512;   // 4,194,304 elems
    const size_t WS_ = (size_t)512 * 512;

    // ws layout (bf16 elems): [slotA: conv inputs / num partials][qs][ks][vT][Wc x3][bc x3][denom f32]
    auto need = [&](size_t sa, int ns) -> size_t {
        return (sa + 3 * M) * 2 + 3 * WS_ * 2 + 3 * 512 * 2 + 64 + (size_t)ns * 8192 * 4;
    };
    int nsplit; size_t sa; bool batched;
    if      (ws_size >= need(8 * M, 8)) { nsplit = 8; sa = 8 * M; batched = true; }
    else if (ws_size >= need(4 * M, 4)) { nsplit = 4; sa = 4 * M; batched = true; }
    else if (ws_size >= need(3 * M, 2)) { nsplit = 2; sa = 3 * M; batched = true; }
    else                                { nsplit = 1; sa = 1 * M; batched = false; }

    unsigned short* ws    = (unsigned short*)d_ws;
    unsigned short* slotA = ws;                 // conv inputs, later numb
    unsigned short* qs    = ws + sa;
    unsigned short* ks    = qs + M;
    unsigned short* vT    = ks + M;
    unsigned short* Wc    = vT + M;             // 3 slots stride WS_
    unsigned short* bc    = Wc + 3 * WS_;       // 3 slots stride 512
    float* denom = (float*)(((uintptr_t)(bc + 3 * 512) + 15) & ~(uintptr_t)15);
    unsigned short* numb = slotA;

    const float qscale = 1.0f / sqrtf(512.0f);

    conv_wb_kernel<<<dim3(257, 3), dim3(256), 0, stream>>>(Wq, Wk, Wv, bq, bk, bv, Wc, bc);

    if (batched) {
        conv_qkv_kernel<<<dim3(3 * 4096), dim3(256), 0, stream>>>(Qin, Kin, Vin, slotA);
        proj_kernel<<<dim3(256, 3), dim3(256), 0, stream>>>(
            slotA, M, 0, Wc, bc, qs, ks, vT, qscale);
    } else {
        const float* Xin[3] = { Qin, Kin, Vin };
        for (int m = 0; m < 3; m++) {
            conv1_kernel<<<dim3(4096), dim3(256), 0, stream>>>(Xin[m], slotA);
            proj_kernel<<<dim3(256, 1), dim3(256), 0, stream>>>(
                slotA, 0, m, Wc, bc, qs, ks, vT, qscale);
        }
    }

    if (nsplit == 8)
        attn_kernel<8><<<dim3(1024), dim3(256), 0, stream>>>(qs, ks, vT, numb, denom);
    else if (nsplit == 4)
        attn_kernel<4><<<dim3(512), dim3(256), 0, stream>>>(qs, ks, vT, numb, denom);
    else if (nsplit == 2)
        attn_kernel<2><<<dim3(256), dim3(256), 0, stream>>>(qs, ks, vT, numb, denom);
    else
        attn_kernel<1><<<dim3(128), dim3(256), 0, stream>>>(qs, ks, vT, numb, denom);

    combine_kernel<<<dim3(2048), dim3(256), 0, stream>>>(
        numb, denom, (float*)d_out, nsplit);
}

// Round 6
// 224.857 us; speedup vs baseline: 1.3868x; 1.1560x over previous
//
#include <hip/hip_runtime.h>
#include <hip/hip_bf16.h>
#include <math.h>
#include <stdint.h>

// ---------- types ----------
typedef __attribute__((ext_vector_type(8))) short short8;     // 8 x bf16 (MFMA A/B frag)
typedef __attribute__((ext_vector_type(4))) float floatx4;    // MFMA C/D frag
typedef __attribute__((ext_vector_type(4))) unsigned short ushort4v;

// ---------- helpers ----------
__device__ __forceinline__ void gload_lds16(const void* g, void* lds) {
    __builtin_amdgcn_global_load_lds(
        (__attribute__((address_space(1))) void*)(g),
        (__attribute__((address_space(3))) void*)(lds), 16, 0, 0);
}
__device__ __forceinline__ float bf16bits_to_f(unsigned short u) {
    union { unsigned int i; float f; } x; x.i = ((unsigned int)u) << 16; return x.f;
}
__device__ __forceinline__ unsigned short f_to_bf16bits(float f) {
    union { float f; unsigned int i; } x; x.f = f;
    unsigned int lsb = (x.i >> 16) & 1u;
    x.i += 0x7fffu + lsb;                      // round-to-nearest-even
    return (unsigned short)(x.i >> 16);
}

// =====================================================================
// One-dispatch fp32->bf16 conversion: Q,K,V (12288 blocks) + W x3 (768) +
// b x3 (3). grid 13059.
// =====================================================================
__global__ __launch_bounds__(256) void conv_all_kernel(
    const float* __restrict__ Q, const float* __restrict__ K, const float* __restrict__ V,
    const float* __restrict__ Wq, const float* __restrict__ Wk, const float* __restrict__ Wv,
    const float* __restrict__ bq, const float* __restrict__ bk, const float* __restrict__ bv,
    unsigned short* __restrict__ qkv,  // 3 slots stride 4194304
    unsigned short* __restrict__ Wo,   // 3 slots stride 262144
    unsigned short* __restrict__ bo)   // 3 slots stride 512
{
    const int gid = blockIdx.x;
    const float* src; unsigned short* dst; int idx;
    if (gid < 12288) {
        const int seg = gid >> 12, blk = gid & 4095;
        src = (seg == 0) ? Q : (seg == 1) ? K : V;
        dst = qkv + (size_t)seg * 4194304;
        idx = (blk * 256 + threadIdx.x) * 4;
    } else if (gid < 13056) {
        const int t = gid - 12288, m = t >> 8, blk = t & 255;
        src = (m == 0) ? Wq : (m == 1) ? Wk : Wv;
        dst = Wo + (size_t)m * 262144;
        idx = (blk * 256 + threadIdx.x) * 4;
    } else {
        const int m = gid - 13056;
        if (threadIdx.x >= 128) return;
        src = (m == 0) ? bq : (m == 1) ? bk : bv;
        dst = bo + (size_t)m * 512;
        idx = threadIdx.x * 4;
    }
    float4 v = *(const float4*)&src[idx];
    ushort4v o;
    o[0] = f_to_bf16bits(v.x); o[1] = f_to_bf16bits(v.y);
    o[2] = f_to_bf16bits(v.z); o[3] = f_to_bf16bits(v.w);
    *(ushort4v*)&dst[idx] = o;
}

// single-input fp32 -> bf16 (small-ws fallback). grid 4096.
__global__ __launch_bounds__(256) void conv1_kernel(
    const float* __restrict__ in, unsigned short* __restrict__ out)
{
    const int idx = (blockIdx.x * 256 + threadIdx.x) * 4;
    float4 v = *(const float4*)&in[idx];
    ushort4v o;
    o[0] = f_to_bf16bits(v.x); o[1] = f_to_bf16bits(v.y);
    o[2] = f_to_bf16bits(v.z); o[3] = f_to_bf16bits(v.w);
    *(ushort4v*)&out[idx] = o;
}

// W/b conversion only (fallback path). grid (257,3).
__global__ __launch_bounds__(256) void conv_wb_kernel(
    const float* __restrict__ Wq, const float* __restrict__ Wk, const float* __restrict__ Wv,
    const float* __restrict__ bq, const float* __restrict__ bk, const float* __restrict__ bv,
    unsigned short* __restrict__ Wo, unsigned short* __restrict__ bo)
{
    const int m = blockIdx.y;
    const float* W = (m == 0) ? Wq : (m == 1) ? Wk : Wv;
    const float* b = (m == 0) ? bq : (m == 1) ? bk : bv;
    if (blockIdx.x < 256) {
        const int idx = (blockIdx.x * 256 + threadIdx.x) * 4;
        float4 v = *(const float4*)&W[idx];
        ushort4v o;
        o[0] = f_to_bf16bits(v.x); o[1] = f_to_bf16bits(v.y);
        o[2] = f_to_bf16bits(v.z); o[3] = f_to_bf16bits(v.w);
        *(ushort4v*)&Wo[(size_t)m * 262144 + idx] = o;
    } else if (threadIdx.x < 128) {
        const int idx = threadIdx.x * 4;
        float4 v = *(const float4*)&b[idx];
        ushort4v o;
        o[0] = f_to_bf16bits(v.x); o[1] = f_to_bf16bits(v.y);
        o[2] = f_to_bf16bits(v.z); o[3] = f_to_bf16bits(v.w);
        *(ushort4v*)&bo[(size_t)m * 512 + idx] = o;
    }
}

// =====================================================================
// Projection: C[m,n] = sum_k X[m,k]*W[n,k] + b[n]. M=8192,N=512,K=512.
// grid (256, nmodes); mode = mode_base + blockIdx.y.
// mode 0: q (scaled), 1: k, 2: v stored in PV-B-frag-native layout:
//   V6 elem(b,d,k) at  b*2097152 + (d>>4)*65536 + (k>>3)*128 + (d&15)*8 + (k&7)
// =====================================================================
__global__ __launch_bounds__(256, 2) void proj_kernel(
    const unsigned short* __restrict__ Xall,
    size_t xstride, int mode_base,
    const unsigned short* __restrict__ Wall,  // 3 slots stride 262144
    const unsigned short* __restrict__ ball,  // 3 slots stride 512
    unsigned short* __restrict__ qbuf,        // [8192,512] pre-scaled
    unsigned short* __restrict__ kbuf,        // [8192,512]
    unsigned short* __restrict__ vTbuf,       // V6 layout, 2*2097152 elems
    float qscale)
{
    __shared__ __align__(16) unsigned short Xs[128 * 64];
    __shared__ __align__(16) unsigned short Ws[128 * 64];

    const int mode = mode_base + blockIdx.y;
    const unsigned short* X = Xall + (size_t)blockIdx.y * xstride;
    const unsigned short* W = Wall + (size_t)mode * 262144;
    const unsigned short* bias = ball + (size_t)mode * 512;

    const int tid = threadIdx.x;
    const int wave = tid >> 6, lane = tid & 63, quad = lane >> 4, l15 = lane & 15;
    const int m0 = (int)(blockIdx.x >> 2) << 7;
    const int n0 = (int)(blockIdx.x & 3) << 7;
    const int mw = (wave >> 1) << 6, nw = (wave & 1) << 6;

    floatx4 acc[4][4];
    #pragma unroll
    for (int i = 0; i < 4; i++)
        #pragma unroll
        for (int j = 0; j < 4; j++) acc[i][j] = floatx4{0.f, 0.f, 0.f, 0.f};

    for (int kt = 0; kt < 512; kt += 64) {
        #pragma unroll
        for (int i = 0; i < 4; i++) {
            const int r0 = wave * 32 + i * 8;
            gload_lds16(X + (size_t)(m0 + r0 + (lane >> 3)) * 512 + kt + (lane & 7) * 8, &Xs[r0 * 64]);
            gload_lds16(W + (size_t)(n0 + r0 + (lane >> 3)) * 512 + kt + (lane & 7) * 8, &Ws[r0 * 64]);
        }
        __syncthreads();
        #pragma unroll
        for (int kk = 0; kk < 64; kk += 32) {
            short8 a[4], b[4];
            #pragma unroll
            for (int i = 0; i < 4; i++) a[i] = *(const short8*)&Xs[(mw + 16 * i + l15) * 64 + kk + quad * 8];
            #pragma unroll
            for (int j = 0; j < 4; j++) b[j] = *(const short8*)&Ws[(nw + 16 * j + l15) * 64 + kk + quad * 8];
            #pragma unroll
            for (int i = 0; i < 4; i++)
                #pragma unroll
                for (int j = 0; j < 4; j++)
                    acc[i][j] = __builtin_amdgcn_mfma_f32_16x16x32_bf16(a[i], b[j], acc[i][j], 0, 0, 0);
        }
        __syncthreads();
    }

    float bfj[4];
    #pragma unroll
    for (int j = 0; j < 4; j++) bfj[j] = bf16bits_to_f(bias[n0 + nw + 16 * j + l15]);

    if (mode < 2) {
        unsigned short* out = (mode == 0) ? qbuf : kbuf;
        const float s = (mode == 0) ? qscale : 1.0f;
        #pragma unroll
        for (int i = 0; i < 4; i++) {
            const int mrow = m0 + mw + 16 * i + quad * 4;   // C/D: row = quad*4+reg
            #pragma unroll
            for (int j = 0; j < 4; j++) {
                const int n = n0 + nw + 16 * j + l15;       // C/D: col = lane&15
                #pragma unroll
                for (int r = 0; r < 4; r++)
                    out[(size_t)(mrow + r) * 512 + n] = f_to_bf16bits((acc[i][j][r] + bfj[j]) * s);
            }
        }
    } else {
        // V6 layout: 4 consecutive keys -> 8B store (k4 % 4 == 0, k4&7 in {0,4})
        #pragma unroll
        for (int i = 0; i < 4; i++) {
            const int mrow = m0 + mw + 16 * i + quad * 4;
            const int bb = mrow >> 12;
            const int k4 = mrow & 4095;
            const size_t kpart = (size_t)bb * 2097152 + (size_t)(k4 >> 3) * 128 + (k4 & 7);
            #pragma unroll
            for (int j = 0; j < 4; j++) {
                const int n = n0 + nw + 16 * j + l15;
                ushort4v pk;
                #pragma unroll
                for (int r = 0; r < 4; r++) pk[r] = f_to_bf16bits(acc[i][j][r] + bfj[j]);
                *(ushort4v*)&vTbuf[kpart + (size_t)(n >> 4) * 65536 + (n & 15) * 8] = pk;
            }
        }
    }
}

// =====================================================================
// Flash attention v3: V read coalesced global->reg via V6 layout (no V LDS),
// 2 barriers/iter. WG = 4 waves, BQ=64 q-rows, TK=32 keys, key-split NSPLIT.
// S-phase: wave owns 16 q-rows (Q frags in regs, K from LDS).
// PV-phase: wave owns d-cols [128w,128w+128); V frags loaded after B1.
// LDS = Ks 33.3 KB + Ps 5 KB.
// num is stored permuted: num[sp][row][wave][l15][c] for b128 stores.
// =====================================================================
template <int NSPLIT>
__global__ __launch_bounds__(256, 2) void attn_kernel(
    const unsigned short* __restrict__ q,    // [8192,512] pre-scaled
    const unsigned short* __restrict__ k,    // [8192,512]
    const unsigned short* __restrict__ vT,   // V6 layout
    unsigned short* __restrict__ num,        // [NSPLIT,8192,512] permuted bf16 partials
    float* __restrict__ denom)               // [NSPLIT,8192]
{
    constexpr int TK  = 32;
    constexpr int KST = 520;   // 512 + 8 pad
    constexpr int PST = 40;    // 32 + 8 pad
    __shared__ __align__(16) unsigned short Ks[TK * KST];   // 33.3 KB
    __shared__ __align__(16) unsigned short Ps[64 * PST];   // 5 KB

    const int tid = threadIdx.x;
    const int wave = tid >> 6, lane = tid & 63, quad = lane >> 4, l15 = lane & 15;
    const int bid = blockIdx.x;
    const int sp   = bid & (NSPLIT - 1);
    const int qblk = bid / NSPLIT;
    const int bb = qblk >> 6;              // batch
    const int q0 = (qblk & 63) << 6;       // q-tile start within batch
    const size_t rowbase = (size_t)bb * 4096 + q0;

    // Q fragments for this wave's 16 rows: A[m=lane&15][k=quad*8+j], 16 k-steps
    short8 qf[16];
    {
        const unsigned short* qrow = q + (rowbase + 16 * wave + l15) * 512;
        #pragma unroll
        for (int t = 0; t < 16; t++) qf[t] = *(const short8*)&qrow[t * 32 + quad * 8];
    }

    floatx4 oacc[4][8];                    // rows 16i+quad*4+r, cols 128*wave+16c+l15
    #pragma unroll
    for (int i = 0; i < 4; i++)
        #pragma unroll
        for (int c = 0; c < 8; c++) oacc[i][c] = floatx4{0.f, 0.f, 0.f, 0.f};
    float dsum[4] = {0.f, 0.f, 0.f, 0.f};

    const unsigned short* kb = k + (size_t)bb * 4096 * 512;
    // V6 per-lane base for this wave: dblk = 8*wave + c
    const unsigned short* vbase = vT + (size_t)bb * 2097152
                                + (size_t)(8 * wave) * 65536 + quad * 128 + l15 * 8;

    const int jbeg = sp * (4096 / NSPLIT);
    const int jend = jbeg + (4096 / NSPLIT);
    for (int j0 = jbeg; j0 < jend; j0 += TK) {
        // --- stage K tile (32 rows x 512) async ---
        #pragma unroll
        for (int r = 0; r < 8; r++) {
            const int row = wave * 8 + r;                       // one 1KB row per issue
            gload_lds16(kb + (size_t)(j0 + row) * 512 + lane * 8, &Ks[row * KST]);
        }
        __syncthreads();   // B1: K staged

        // --- V fragments: fully-coalesced 1KB loads, land during S-phase ---
        short8 vf[8];
        #pragma unroll
        for (int c = 0; c < 8; c++)
            vf[c] = *(const short8*)&vbase[(size_t)c * 65536 + (j0 << 4)];

        // --- S = q . K^T for this wave's 16 rows x 32 keys ---
        floatx4 sA[2], sB[2];
        sA[0] = sA[1] = sB[0] = sB[1] = floatx4{0.f, 0.f, 0.f, 0.f};
        #pragma unroll
        for (int t = 0; t < 16; t += 2) {
            #pragma unroll
            for (int c = 0; c < 2; c++) {
                short8 b0 = *(const short8*)&Ks[(c * 16 + l15) * KST + t * 32 + quad * 8];
                sA[c] = __builtin_amdgcn_mfma_f32_16x16x32_bf16(qf[t], b0, sA[c], 0, 0, 0);
                short8 b1 = *(const short8*)&Ks[(c * 16 + l15) * KST + (t + 1) * 32 + quad * 8];
                sB[c] = __builtin_amdgcn_mfma_f32_16x16x32_bf16(qf[t + 1], b1, sB[c], 0, 0, 0);
            }
        }
        // --- P = exp(S); accumulate denom with the bf16-rounded value ---
        #pragma unroll
        for (int c = 0; c < 2; c++) {
            #pragma unroll
            for (int r = 0; r < 4; r++) {
                const float p = __expf(fminf(sA[c][r] + sB[c][r], 30.0f));
                const unsigned short pb = f_to_bf16bits(p);
                dsum[r] += bf16bits_to_f(pb);
                Ps[(16 * wave + quad * 4 + r) * PST + c * 16 + l15] = pb;
            }
        }
        __syncthreads();   // B2: P complete before cross-wave A-frag reads

        // --- O[0:64][128w:128w+128] += P @ V (A from LDS, B from regs) ---
        // no 3rd barrier: next iter's B1 orders PV Ps-reads vs next P-writes
        short8 ap[4];
        #pragma unroll
        for (int i = 0; i < 4; i++) ap[i] = *(const short8*)&Ps[(16 * i + l15) * PST + quad * 8];
        #pragma unroll
        for (int c = 0; c < 8; c++) {
            #pragma unroll
            for (int i = 0; i < 4; i++)
                oacc[i][c] = __builtin_amdgcn_mfma_f32_16x16x32_bf16(ap[i], vf[c], oacc[i][c], 0, 0, 0);
        }
    }

    // row-sum the per-lane denominator partials
    #pragma unroll
    for (int r = 0; r < 4; r++) {
        float v = dsum[r];
        v += __shfl_xor(v, 1);
        v += __shfl_xor(v, 2);
        v += __shfl_xor(v, 4);
        v += __shfl_xor(v, 8);
        dsum[r] = v;
    }
    if (l15 == 0) {
        #pragma unroll
        for (int r = 0; r < 4; r++)
            denom[(size_t)sp * 8192 + rowbase + 16 * wave + quad * 4 + r] = dsum[r];
    }

    // store bf16 numerator partials, permuted: [row][wave][l15][c] -> b128
    #pragma unroll
    for (int i = 0; i < 4; i++) {
        #pragma unroll
        for (int r = 0; r < 4; r++) {
            const size_t row = rowbase + 16 * i + quad * 4 + r;
            short8 pk;
            #pragma unroll
            for (int c = 0; c < 8; c++) pk[c] = (short)f_to_bf16bits(oacc[i][c][r]);
            *(short8*)&num[((size_t)sp * 8192 + row) * 512 + wave * 128 + l15 * 8] = pk;
        }
    }
}

// =====================================================================
// Combine: out = (sum_sp num) / (sum_sp denom), fp32 out.
// thread = (srow, w, l15); reads permuted num as b128, writes 8 dwords
// at d = w*128 + 16c + l15.
// =====================================================================
__global__ __launch_bounds__(256) void combine_kernel(
    const unsigned short* __restrict__ num,
    const float* __restrict__ denom,
    float* __restrict__ out,
    int nsplit)
{
    const int gid = blockIdx.x * 256 + threadIdx.x;
    const int srow = gid >> 6;            // 0..8191
    const int sub = gid & 63;
    const int w = sub >> 4, l15 = sub & 15;
    float s[8];
    #pragma unroll
    for (int e = 0; e < 8; e++) s[e] = 0.f;
    float den = 0.f;
    for (int sp = 0; sp < nsplit; sp++) {
        den += denom[(size_t)sp * 8192 + srow];
        short8 v = *(const short8*)(num + ((size_t)sp * 8192 + srow) * 512 + w * 128 + l15 * 8);
        #pragma unroll
        for (int e = 0; e < 8; e++) s[e] += bf16bits_to_f((unsigned short)v[e]);
    }
    const float inv = 1.0f / den;
    float* op = out + (size_t)srow * 512 + w * 128 + l15;
    #pragma unroll
    for (int c = 0; c < 8; c++) op[16 * c] = s[c] * inv;
}

// =====================================================================
extern "C" void kernel_launch(void* const* d_in, const int* in_sizes, int n_in,
                              void* d_out, int out_size, void* d_ws, size_t ws_size,
                              hipStream_t stream)
{
    (void)in_sizes; (void)n_in; (void)out_size;
    const float* Qin = (const float*)d_in[0];
    const float* Kin = (const float*)d_in[1];
    const float* Vin = (const float*)d_in[2];
    const float* Wq  = (const float*)d_in[3];
    const float* bq  = (const float*)d_in[4];
    const float* Wk  = (const float*)d_in[5];
    const float* bk  = (const float*)d_in[6];
    const float* Wv  = (const float*)d_in[7];
    const float* bv  = (const float*)d_in[8];

    const size_t M   = (size_t)8192 * 512;   // 4,194,304 elems
    const size_t WS_ = (size_t)512 * 512;

    // ws layout (bf16 elems): [slotA: conv inputs / num partials][qs][ks][vT][Wc x3][bc x3][denom f32]
    auto need = [&](size_t sa, int ns) -> size_t {
        return (sa + 3 * M) * 2 + 3 * WS_ * 2 + 3 * 512 * 2 + 64 + (size_t)ns * 8192 * 4;
    };
    int nsplit; size_t sa; bool batched;
    if      (ws_size >= need(4 * M, 4)) { nsplit = 4; sa = 4 * M; batched = true; }
    else if (ws_size >= need(3 * M, 2)) { nsplit = 2; sa = 3 * M; batched = true; }
    else                                { nsplit = 1; sa = 1 * M; batched = false; }

    unsigned short* ws    = (unsigned short*)d_ws;
    unsigned short* slotA = ws;                 // conv inputs, later numb
    unsigned short* qs    = ws + sa;
    unsigned short* ks    = qs + M;
    unsigned short* vT    = ks + M;
    unsigned short* Wc    = vT + M;             // 3 slots stride WS_
    unsigned short* bc    = Wc + 3 * WS_;       // 3 slots stride 512
    float* denom = (float*)(((uintptr_t)(bc + 3 * 512) + 15) & ~(uintptr_t)15);
    unsigned short* numb = slotA;

    const float qscale = 1.0f / sqrtf(512.0f);

    if (batched) {
        conv_all_kernel<<<dim3(13059), dim3(256), 0, stream>>>(
            Qin, Kin, Vin, Wq, Wk, Wv, bq, bk, bv, slotA, Wc, bc);
        proj_kernel<<<dim3(256, 3), dim3(256), 0, stream>>>(
            slotA, M, 0, Wc, bc, qs, ks, vT, qscale);
    } else {
        conv_wb_kernel<<<dim3(257, 3), dim3(256), 0, stream>>>(Wq, Wk, Wv, bq, bk, bv, Wc, bc);
        const float* Xin[3] = { Qin, Kin, Vin };
        for (int m = 0; m < 3; m++) {
            conv1_kernel<<<dim3(4096), dim3(256), 0, stream>>>(Xin[m], slotA);
            proj_kernel<<<dim3(256, 1), dim3(256), 0, stream>>>(
                slotA, 0, m, Wc, bc, qs, ks, vT, qscale);
        }
    }

    if (nsplit == 4)
        attn_kernel<4><<<dim3(512), dim3(256), 0, stream>>>(qs, ks, vT, numb, denom);
    else if (nsplit == 2)
        attn_kernel<2><<<dim3(256), dim3(256), 0, stream>>>(qs, ks, vT, numb, denom);
    else
        attn_kernel<1><<<dim3(128), dim3(256), 0, stream>>>(qs, ks, vT, numb, denom);

    combine_kernel<<<dim3(2048), dim3(256), 0, stream>>>(
        numb, denom, (float*)d_out, nsplit);
}